// Round 8
// baseline (382.859 us; speedup 1.0000x reference)
//
#include <hip/hip_runtime.h>
#include <hip/hip_bf16.h>
#include <stdint.h>

// ---------------------------------------------------------------------------
// Decoder (teacher-forced, state never advances):
//   gates = x @ W_ih^T + (h0 @ W_hh^T + b_ih + b_hh)  (broadcast over t)
//   i,f,g,o = split(gates); c' = sig(f)*c0 + sig(i)*tanh(g); h' = sig(o)*tanh(c')
//   out = h' @ fc_w^T + fc_b
// Sizes: B=64, T=1024, D=513, H=512, 4H=2048.  M = B*T = 65536.
// R7: instruction diet. Full unroll of the triple-buffer K-loop so buffer
//     rotation and ALL addresses (LDS + global) fold into immediates:
//     per-K-tile VALU ~0 (was ~25-30/wave). Structure otherwise = R6:
//     512 thr / 8 waves (4Mx2N), tile 256x128, BK=32, 3x24KB LDS,
//     one barrier + counted vmcnt(3) per K-tile, fragment-ordered
//     0-conflict LDS, setprio, XCD swizzle, gate-interleaved W.
// ---------------------------------------------------------------------------

typedef __bf16 bf16x8 __attribute__((ext_vector_type(8)));
typedef float f32x4 __attribute__((ext_vector_type(4)));

#define MFMA_BF16 __builtin_amdgcn_mfma_f32_16x16x32_bf16

__device__ __forceinline__ void gld16(const void* gptr, void* lptr) {
  __builtin_amdgcn_global_load_lds(
      (const __attribute__((address_space(1))) void*)gptr,
      (__attribute__((address_space(3))) void*)lptr, 16, 0, 0);
}

__device__ __forceinline__ float fsigm(float x) {
  x = fminf(fmaxf(x, -30.f), 30.f);
  return __frcp_rn(1.f + __expf(-x));
}
__device__ __forceinline__ float ftanh(float x) {
  x = fminf(fmaxf(x, -15.f), 15.f);
  const float e = __expf(2.f * x);
  return (e - 1.f) * __frcp_rn(e + 1.f);
}

// --------------------------- pack fp32 -> bf16 ------------------------------
__global__ void pack_bf16_kernel(const float* __restrict__ in,
                                 __bf16* __restrict__ out,
                                 int rows_in, int kin, int kout) {
  const int r = blockIdx.x;
  const bool rv = r < rows_in;
  for (int c = threadIdx.x * 2; c < kout; c += 512) {
    float v0 = (rv && c < kin) ? in[(size_t)r * kin + c] : 0.f;
    float v1 = (rv && c + 1 < kin) ? in[(size_t)r * kin + c + 1] : 0.f;
    union { __bf16 h[2]; uint32_t u; } p;
    p.h[0] = (__bf16)v0;
    p.h[1] = (__bf16)v1;
    *(uint32_t*)&out[(size_t)r * kout + c] = p.u;
  }
}

// pack W_ih gate-interleaved: packed row p -> gate (p>>4)&3, h (p>>6)*16+(p&15)
__global__ void pack_wih_kernel(const float* __restrict__ Wih,
                                __bf16* __restrict__ wpk) {
  const int p = blockIdx.x;  // 0..2047
  const int g = (p >> 4) & 3;
  const int h = ((p >> 6) << 4) + (p & 15);
  const float* src = Wih + (size_t)(g * 512 + h) * 513;
  for (int c = threadIdx.x * 2; c < 544; c += 512) {
    float v0 = (c < 513) ? src[c] : 0.f;
    float v1 = (c + 1 < 513) ? src[c + 1] : 0.f;
    union { __bf16 hh[2]; uint32_t u; } pk;
    pk.hh[0] = (__bf16)v0;
    pk.hh[1] = (__bf16)v1;
    *(uint32_t*)&wpk[(size_t)p * 544 + c] = pk.u;
  }
}

// --------------------------- hbias ------------------------------------------
__global__ void hbias_kernel(const float* __restrict__ h0,
                             const float* __restrict__ Whh,
                             const float* __restrict__ bih,
                             const float* __restrict__ bhh,
                             float* __restrict__ hbias) {
  const int t = threadIdx.x, w = t >> 6, l = t & 63;
  const int b = blockIdx.x >> 9;
  const int g = ((blockIdx.x & 511) << 2) | w;
  const float* hr = h0 + b * 512;
  const float* wr = Whh + (size_t)g * 512;
  float s = 0.f;
#pragma unroll
  for (int h = 0; h < 512; h += 64) s = fmaf(hr[h + l], wr[h + l], s);
#pragma unroll
  for (int off = 32; off; off >>= 1) s += __shfl_down(s, off);
  if (l == 0) hbias[b * 2048 + g] = s + bih[g] + bhh[g];
}

// --------------------------- triple-buffer GEMM core ------------------------
// Block tile 256x128, BK=32, 8 waves (4M x 2N), per-wave 64x64 (acc[4][4]).
// LDS: 3 buffers x (A 16KB + B 8KB) = 72KB. Tile kt reads buf kt%3, stages
// tile kt+2 into (kt+2)%3; one barrier/tile; steady gate vmcnt(3).
// FULLY UNROLLED: buffer indices and all LDS/global offsets are immediates.
// Subtile = 16 rows x 32 k fragment-ordered: gld16 dest and ds_read are both
// identity (base + lane*16) -> 0 bank conflicts.
template <int NKT, int KSTR>
__device__ __forceinline__ void gemm_core(
    const __bf16* __restrict__ A, const __bf16* __restrict__ B,
    size_t m0, int n0, char* lds, f32x4 (&acc)[4][4],
    int wid, int l, int wm, int wc) {
  const int lr = l & 15, lq = l >> 4;
  // loop-invariant base pointers; per-tile deltas are small compile-time
  // constants (<= 1024B) that fold into the 13-bit global offset immediate.
  const __bf16* ag = A + (m0 + wid * 16 + lr) * KSTR + lq * 8;
  const __bf16* ag2 = ag + (size_t)128 * KSTR;
  const __bf16* bg = B + (size_t)(n0 + wid * 16 + lr) * KSTR + lq * 8;
  const int sdA = wid << 10;                    // A subtile wid (+8192: wid+8)
  const int sdB = 16384 + (wid << 10);          // B subtile wid
  const int ra = (wm << 12) + l * 16;           // A read: subtile wm*4+mi
  const int rbB = 16384 + (wc << 12) + l * 16;  // B read: subtile wc*4+ni

  // prologue: stage K-tiles 0 and 1 into buffers 0 and 1
#pragma unroll
  for (int p = 0; p < 2; ++p) {
    char* base = lds + p * 24576;
    gld16(ag + p * 32, base + sdA);
    gld16(ag2 + p * 32, base + sdA + 8192);
    gld16(bg + p * 32, base + sdB);
  }
  asm volatile("s_waitcnt vmcnt(3)" ::: "memory");  // tile-0 stage landed
  __builtin_amdgcn_s_barrier();

#pragma unroll
  for (int kt = 0; kt < NKT; ++kt) {
    const int rbuf = kt % 3;             // compile-time after unroll
    const int wbuf = (kt + 2) % 3;
    char* rbase = lds + rbuf * 24576;
    if (kt + 2 < NKT) {  // stage tile kt+2 into the buffer freed at kt-1
      char* wbase = lds + wbuf * 24576;
      const int kof = (kt + 2) * 32;     // <= 1024B delta: folds into imm
      gld16(ag + kof, wbase + sdA);
      gld16(ag2 + kof, wbase + sdA + 8192);
      gld16(bg + kof, wbase + sdB);
    }
    bf16x8 af[4], bq[4];
#pragma unroll
    for (int i = 0; i < 4; ++i)
      af[i] = *(const bf16x8*)(rbase + ra + i * 1024);
#pragma unroll
    for (int i = 0; i < 4; ++i)
      bq[i] = *(const bf16x8*)(rbase + rbB + i * 1024);
    __builtin_amdgcn_s_setprio(1);
#pragma unroll
    for (int mi = 0; mi < 4; ++mi)
#pragma unroll
      for (int ni = 0; ni < 4; ++ni)
        acc[mi][ni] = MFMA_BF16(af[mi], bq[ni], acc[mi][ni], 0, 0, 0);
    __builtin_amdgcn_s_setprio(0);
    if (kt + 2 < NKT) {
      asm volatile("s_waitcnt vmcnt(3)" ::: "memory");  // tile kt+1 landed
    } else if (kt + 1 < NKT) {
      asm volatile("s_waitcnt vmcnt(0)" ::: "memory");  // tail: last tile
    }
    asm volatile("" ::: "memory");
    __builtin_amdgcn_s_barrier();
  }
}

// --------------------------- GEMM1 + LSTM cell ------------------------------
// A = xbf [65536 x 544], B = wpk [2048 x 544] gate-interleaved.
// grid 4096 = 256 m-tiles x 16 n-tiles.
__global__ __launch_bounds__(512, 4) void gemm1_kernel(
    const __bf16* __restrict__ xbf, const __bf16* __restrict__ wpk,
    const float* __restrict__ hbias, const float* __restrict__ c0,
    __bf16* __restrict__ hnew) {
  const int t = threadIdx.x, wid = t >> 6, l = t & 63;
  const int wm = wid >> 1, wc = wid & 1;
  const int bid = blockIdx.x;
  const int swz = (bid & 7) * 512 + (bid >> 3);  // XCD-contiguous
  const size_t m0 = (size_t)(swz >> 4) << 8;
  const int n0 = (swz & 15) << 7;

  __shared__ __align__(16) char lds[73728];

  f32x4 acc[4][4];
#pragma unroll
  for (int mi = 0; mi < 4; ++mi)
#pragma unroll
    for (int ni = 0; ni < 4; ++ni) acc[mi][ni] = (f32x4){0.f, 0.f, 0.f, 0.f};

  gemm_core<17, 544>(xbf, wpk, m0, n0, lds, acc, wid, l, wm, wc);

  // lane's packed col p = n0 + wc*64 + ni*16 + (l&15) -> gate = ni,
  // h = (n0/64 + wc)*16 + (l&15). All 4 gates lane-local.
  const int lr = l & 15, lq = l >> 4;
  const int hcol = (((n0 >> 6) + wc) << 4) + lr;
  const int b = (int)(m0 >> 10);
  const float hb0 = hbias[b * 2048 + hcol];
  const float hb1 = hbias[b * 2048 + 512 + hcol];
  const float hb2 = hbias[b * 2048 + 1024 + hcol];
  const float hb3 = hbias[b * 2048 + 1536 + hcol];
  const float c0v = c0[b * 512 + hcol];
#pragma unroll
  for (int mi = 0; mi < 4; ++mi) {
#pragma unroll
    for (int r = 0; r < 4; ++r) {
      const size_t m = m0 + wm * 64 + mi * 16 + lq * 4 + r;
      const float gi = acc[mi][0][r] + hb0;
      const float gf = acc[mi][1][r] + hb1;
      const float gg = acc[mi][2][r] + hb2;
      const float go = acc[mi][3][r] + hb3;
      const float cn = fsigm(gf) * c0v + fsigm(gi) * ftanh(gg);
      hnew[m * 512 + hcol] = (__bf16)(fsigm(go) * ftanh(cn));
    }
  }
}

// --------------------------- GEMM2 + bias -----------------------------------
// A = hnew [65536 x 512], B = fwbf [640 x 512] (rows 513.. zero).
// grid 1280 = 256 m-tiles x 5 n-tiles.
__global__ __launch_bounds__(512, 4) void gemm2_kernel(
    const __bf16* __restrict__ hnew, const __bf16* __restrict__ fcw,
    const float* __restrict__ fcb, float* __restrict__ out) {
  const int t = threadIdx.x, wid = t >> 6, l = t & 63;
  const int wm = wid >> 1, wc = wid & 1;
  const int bid = blockIdx.x;
  const int swz = (bid & 7) * 160 + (bid >> 3);
  const size_t m0 = (size_t)(swz / 5) << 8;
  const int n0 = (swz % 5) << 7;

  __shared__ __align__(16) char lds[73728];

  f32x4 acc[4][4];
#pragma unroll
  for (int mi = 0; mi < 4; ++mi)
#pragma unroll
    for (int ni = 0; ni < 4; ++ni) acc[mi][ni] = (f32x4){0.f, 0.f, 0.f, 0.f};

  gemm_core<16, 512>(hnew, fcw, m0, n0, lds, acc, wid, l, wm, wc);

  const int lr = l & 15, lq = l >> 4;
#pragma unroll
  for (int ni = 0; ni < 4; ++ni) {
    const int n = n0 + wc * 64 + ni * 16 + lr;
    if (n < 513) {
      const float bias = fcb[n];
#pragma unroll
      for (int mi = 0; mi < 4; ++mi) {
#pragma unroll
        for (int r = 0; r < 4; ++r) {
          const size_t m = m0 + wm * 64 + mi * 16 + lq * 4 + r;
          out[m * 513 + n] = acc[mi][ni][r] + bias;
        }
      }
    }
  }
}

// --------------------------- launch -----------------------------------------
extern "C" void kernel_launch(void* const* d_in, const int* in_sizes, int n_in,
                              void* d_out, int out_size, void* d_ws, size_t ws_size,
                              hipStream_t stream) {
  const float* x = (const float*)d_in[0];     // [64,1024,513]
  const float* h0 = (const float*)d_in[1];    // [1,64,512]
  const float* c0 = (const float*)d_in[2];    // [1,64,512]
  const float* Wih = (const float*)d_in[3];   // [2048,513]
  const float* Whh = (const float*)d_in[4];   // [2048,512]
  const float* bih = (const float*)d_in[5];   // [2048]
  const float* bhh = (const float*)d_in[6];   // [2048]
  const float* fcw = (const float*)d_in[7];   // [513,512]
  const float* fcb = (const float*)d_in[8];   // [513]
  float* out = (float*)d_out;                 // [64,1024,513]

  char* ws = (char*)d_ws;
  __bf16* xbf = (__bf16*)(ws);                 // 65536*544*2 = 71,303,168
  __bf16* wpk = (__bf16*)(ws + 71303168);      //  2048*544*2 =  2,228,224
  __bf16* fwbf = (__bf16*)(ws + 73531392);     //   640*512*2 =    655,360
  float* hb = (float*)(ws + 74186752);         //   64*2048*4 =    524,288
  __bf16* hn = (__bf16*)(ws + 74711040);       // 65536*512*2 = 67,108,864
  // total ws use: 141,819,904 bytes

  pack_bf16_kernel<<<65536, 256, 0, stream>>>(x, xbf, 65536, 513, 544);
  pack_wih_kernel<<<2048, 256, 0, stream>>>(Wih, wpk);
  pack_bf16_kernel<<<640, 256, 0, stream>>>(fcw, fwbf, 513, 512, 512);
  hbias_kernel<<<32768, 256, 0, stream>>>(h0, Whh, bih, bhh, hb);
  gemm1_kernel<<<4096, 512, 0, stream>>>(xbf, wpk, hb, c0, hn);
  gemm2_kernel<<<1280, 512, 0, stream>>>(hn, fwbf, fcb, out);
}